// Round 3
// baseline (1016.643 us; speedup 1.0000x reference)
//
#include <hip/hip_runtime.h>

#define Bsz 16384
#define TT 10
#define FF 500
#define H1c 256
#define H2c 100

typedef _Float16 half8 __attribute__((ext_vector_type(8)));
typedef _Float16 half4 __attribute__((ext_vector_type(4)));
typedef float floatx4 __attribute__((ext_vector_type(4)));

__device__ __forceinline__ float sigm(float x) { return 1.0f / (1.0f + __expf(-x)); }

#define GLOAD16(g, l) __builtin_amdgcn_global_load_lds( \
    (const __attribute__((address_space(1))) void*)(g), \
    (__attribute__((address_space(3))) void*)(l), 16, 0, 0)

// ---------------------------------------------------------------------------
// Convert ALL noise fp32 -> xc fp16, rows are flat (b*10+t), 500 -> 512 pad.
// ---------------------------------------------------------------------------
__global__ __launch_bounds__(256)
void conv_all(const float* __restrict__ noise, _Float16* __restrict__ xc)
{
    const int idx = blockIdx.x * 256 + threadIdx.x;   // 163840*64 threads
    const int row = idx >> 6;
    const int kc = (idx & 63) << 3;
    const float* src = noise + (size_t)row * FF + kc;
    half8 v;
    if (kc + 8 <= FF) {
        float4 u0 = *(const float4*)src;
        float4 u1 = *(const float4*)(src + 4);
        v[0] = (_Float16)u0.x; v[1] = (_Float16)u0.y; v[2] = (_Float16)u0.z; v[3] = (_Float16)u0.w;
        v[4] = (_Float16)u1.x; v[5] = (_Float16)u1.y; v[6] = (_Float16)u1.z; v[7] = (_Float16)u1.w;
    } else {
        #pragma unroll
        for (int j = 0; j < 8; ++j)
            v[j] = (kc + j < FF) ? (_Float16)src[j] : (_Float16)0.f;
    }
    *(half8*)(xc + (size_t)row * 512 + kc) = v;
}

// ---------------------------------------------------------------------------
// LSTM weight prep, n' = 128*(U>>5) + 64*((U>>4)&1) + 16*g + (U&15).
// WTx[n'][0..512) from Wx (500 real rows); WTh[n'][0..256) from Wh.
// ---------------------------------------------------------------------------
__global__ __launch_bounds__(256)
void prep_lstm_w(const float* __restrict__ Wx, const float* __restrict__ Wh,
                 _Float16* __restrict__ WTx, _Float16* __restrict__ WTh)
{
    const int idx = blockIdx.x * 256 + threadIdx.x;   // 1024*768
    const int np = idx / 768, k = idx % 768;
    const int a = np >> 7, b2 = (np >> 6) & 1, g = (np >> 4) & 3, u = np & 15;
    const int U = a * 32 + b2 * 16 + u;
    const int col = g * 256 + U;
    if (k < 512) {
        float v = (k < FF) ? Wx[(size_t)k * 1024 + col] : 0.f;
        WTx[(size_t)np * 512 + k] = (_Float16)v;
    } else {
        WTh[(size_t)np * 256 + (k - 512)] = (_Float16)Wh[(size_t)(k - 512) * 1024 + col];
    }
}

// ---------------------------------------------------------------------------
// GRU weight prep: WT[n'][k], n' = 96*(U>>5) + 48*((U>>4)&1) + 16*g + (U&15),
// U in [0,128) (units padded 100->128). k<256: Wxg rows; k in [256,384): Whg.
// ---------------------------------------------------------------------------
__global__ __launch_bounds__(256)
void prep_gru_w(const float* __restrict__ Wxg, const float* __restrict__ Whg,
                _Float16* __restrict__ WT)
{
    const int idx = blockIdx.x * 256 + threadIdx.x;   // 384*384
    if (idx >= 384 * 384) return;
    const int np = idx / 384, k = idx % 384;
    const int nb = np / 96, rem = np % 96;
    const int wxx = rem / 48, g = (rem % 48) / 16, u = rem & 15;
    const int U = nb * 32 + wxx * 16 + u;
    float v = 0.f;
    if (U < H2c) {
        if (k < 256) v = Wxg[(size_t)k * 300 + g * H2c + U];
        else if (k - 256 < H2c) v = Whg[(size_t)(k - 256) * 300 + g * H2c + U];
    }
    WT[idx] = (_Float16)v;
}

// ---------------------------------------------------------------------------
// Big GEMM: ZX[m][1024] = xc_row(m) @ WTx^T, m = t*16384 + b (t-major planes).
// ZX column storage is fragment-native: c = nb*128 + wx*64 + fr*4 + ni  -> the
// per-lane write is one contiguous half4; lstm_rec reads with same formula.
// 128x128 tile, 4 waves, BK=32, grid(10240) with bijective XCD swizzle.
// ---------------------------------------------------------------------------
__global__ __launch_bounds__(256)
void big_gemm(const _Float16* __restrict__ xc, const _Float16* __restrict__ WTx,
              _Float16* __restrict__ ZX)
{
    __shared__ _Float16 As[128 * 32];
    __shared__ _Float16 Bs[128 * 32];

    const int tid = threadIdx.x;
    const int lane = tid & 63;
    const int w = tid >> 6;
    const int wy = w >> 1, wx = w & 1;
    const int bid = blockIdx.x;
    const int swz = (bid & 7) * 1280 + (bid >> 3);
    const int row0 = (swz >> 3) * 128;          // m-tile base, [0,163840)
    const int nb = swz & 7;
    const int t = row0 >> 14;                   // whole block same t
    const int b0 = row0 & 16383;

    floatx4 acc[4][4];
    #pragma unroll
    for (int a = 0; a < 4; ++a)
        #pragma unroll
        for (int b = 0; b < 4; ++b) acc[a][b] = (floatx4){0.f, 0.f, 0.f, 0.f};

    const int slr = lane >> 2;
    const int slc = (lane & 3) * 8;
    const int fr = lane & 15;
    const int fk = (lane >> 4) * 8;

    for (int kt8 = 0; kt8 < 16; ++kt8) {
        const int kb = kt8 * 32;
        #pragma unroll
        for (int i = 0; i < 2; ++i) {
            const int r = w * 32 + i * 16;
            GLOAD16(WTx + (size_t)(nb * 128 + r + slr) * 512 + kb + slc, &Bs[r * 32]);
        }
        #pragma unroll
        for (int i = 0; i < 2; ++i) {
            const int r = w * 32 + i * 16;
            const int brow = b0 + r + slr;
            GLOAD16(xc + (size_t)(brow * 10 + t) * 512 + kb + slc, &As[r * 32]);
        }
        __syncthreads();
        half8 af[4], bf[4];
        #pragma unroll
        for (int mi = 0; mi < 4; ++mi)
            af[mi] = *(const half8*)&As[(wy * 64 + mi * 16 + fr) * 32 + fk];
        #pragma unroll
        for (int ni = 0; ni < 4; ++ni)
            bf[ni] = *(const half8*)&Bs[(wx * 64 + ni * 16 + fr) * 32 + fk];
        #pragma unroll
        for (int mi = 0; mi < 4; ++mi)
            #pragma unroll
            for (int ni = 0; ni < 4; ++ni)
                acc[mi][ni] = __builtin_amdgcn_mfma_f32_16x16x32_f16(af[mi], bf[ni], acc[mi][ni], 0, 0, 0);
        __syncthreads();
    }

    const size_t cbase = nb * 128 + wx * 64 + fr * 4;
    const int rbase = row0 + wy * 64 + (lane >> 4) * 4;
    #pragma unroll
    for (int mi = 0; mi < 4; ++mi) {
        #pragma unroll
        for (int r = 0; r < 4; ++r) {
            const int row = rbase + mi * 16 + r;
            half4 v;
            v[0] = (_Float16)acc[mi][0][r];
            v[1] = (_Float16)acc[mi][1][r];
            v[2] = (_Float16)acc[mi][2][r];
            v[3] = (_Float16)acc[mi][3][r];
            *(half4*)(ZX + (size_t)row * 1024 + cbase) = v;
        }
    }
}

// ---------------------------------------------------------------------------
// LSTM recurrent step: acc = h_prev @ WTh^T (K=256), z = acc + ZX_t + bias.
// 128x128 tile, 4 waves, grid(1024) with XCD swizzle.
// ---------------------------------------------------------------------------
__global__ __launch_bounds__(256)
void lstm_rec(const _Float16* __restrict__ zx, const _Float16* __restrict__ WTh,
              const float* __restrict__ bias,
              const _Float16* __restrict__ h_prev, const float* __restrict__ c_prev,
              _Float16* __restrict__ h_out, float* __restrict__ c_out, int first)
{
    __shared__ _Float16 As[128 * 32];
    __shared__ _Float16 Bs[128 * 32];

    const int tid = threadIdx.x;
    const int lane = tid & 63;
    const int w = tid >> 6;
    const int wy = w >> 1, wx = w & 1;
    const int bid = blockIdx.x;
    const int swz = (bid & 7) * 128 + (bid >> 3);
    const int row0 = (swz >> 3) * 128;
    const int nb = swz & 7;

    floatx4 acc[4][4];
    #pragma unroll
    for (int a = 0; a < 4; ++a)
        #pragma unroll
        for (int b = 0; b < 4; ++b) acc[a][b] = (floatx4){0.f, 0.f, 0.f, 0.f};

    const int slr = lane >> 2;
    const int slc = (lane & 3) * 8;
    const int fr = lane & 15;
    const int fk = (lane >> 4) * 8;

    if (!first) {
        for (int kt8 = 0; kt8 < 8; ++kt8) {
            const int kb = kt8 * 32;
            #pragma unroll
            for (int i = 0; i < 2; ++i) {
                const int r = w * 32 + i * 16;
                GLOAD16(WTh + (size_t)(nb * 128 + r + slr) * 256 + kb + slc, &Bs[r * 32]);
            }
            #pragma unroll
            for (int i = 0; i < 2; ++i) {
                const int r = w * 32 + i * 16;
                GLOAD16(h_prev + (size_t)(row0 + r + slr) * 256 + kb + slc, &As[r * 32]);
            }
            __syncthreads();
            half8 af[4], bf[4];
            #pragma unroll
            for (int mi = 0; mi < 4; ++mi)
                af[mi] = *(const half8*)&As[(wy * 64 + mi * 16 + fr) * 32 + fk];
            #pragma unroll
            for (int ni = 0; ni < 4; ++ni)
                bf[ni] = *(const half8*)&Bs[(wx * 64 + ni * 16 + fr) * 32 + fk];
            #pragma unroll
            for (int mi = 0; mi < 4; ++mi)
                #pragma unroll
                for (int ni = 0; ni < 4; ++ni)
                    acc[mi][ni] = __builtin_amdgcn_mfma_f32_16x16x32_f16(af[mi], bf[ni], acc[mi][ni], 0, 0, 0);
            __syncthreads();
        }
    }

    // epilogue: lane owns unit U = nb*32 + wx*16 + fr, gate = ni
    const int U = nb * 32 + wx * 16 + fr;
    const float bi = bias[0 * 256 + U];
    const float bff = bias[1 * 256 + U];
    const float bg = bias[2 * 256 + U];
    const float bo = bias[3 * 256 + U];
    const size_t cbase = nb * 128 + wx * 64 + fr * 4;
    const int rbase = row0 + wy * 64 + (lane >> 4) * 4;
    #pragma unroll
    for (int mi = 0; mi < 4; ++mi) {
        #pragma unroll
        for (int r = 0; r < 4; ++r) {
            const int row = rbase + mi * 16 + r;
            half4 zx4 = *(const half4*)(zx + (size_t)row * 1024 + cbase);
            const float cp = first ? 0.f : c_prev[(size_t)row * 256 + U];
            const float zi = acc[mi][0][r] + (float)zx4[0] + bi;
            const float zf = acc[mi][1][r] + (float)zx4[1] + bff;
            const float zg = acc[mi][2][r] + (float)zx4[2] + bg;
            const float zo = acc[mi][3][r] + (float)zx4[3] + bo;
            const float ig = sigm(zi), fg = sigm(zf), og = sigm(zo);
            const float gg = fmaxf(zg, 0.f);
            const float cv = fg * cp + ig * gg;
            const float hv = og * fmaxf(cv, 0.f);
            c_out[(size_t)row * 256 + U] = cv;
            h_out[(size_t)row * 256 + U] = (_Float16)hv;
        }
    }
}

// ---------------------------------------------------------------------------
// GRU step via MFMA. mx = h @ Wxg (K=256), mh = g_prev @ Whg (K=128 padded).
// Block 128x96 (3 gates x 32 units), 4 waves, grid(512) with XCD swizzle.
// ---------------------------------------------------------------------------
__global__ __launch_bounds__(256)
void gru_mfma(const _Float16* __restrict__ hx, const _Float16* __restrict__ WT,
              const float* __restrict__ b_in, const float* __restrict__ b_rec,
              const float* __restrict__ g_prev, const _Float16* __restrict__ g16_prev,
              float* __restrict__ g_out, _Float16* __restrict__ g16_out, int first)
{
    __shared__ _Float16 As[128 * 32];
    __shared__ _Float16 Bs[96 * 32];

    const int tid = threadIdx.x;
    const int lane = tid & 63;
    const int w = tid >> 6;
    const int wy = w >> 1, wx = w & 1;
    const int bid = blockIdx.x;
    const int swz = (bid & 7) * 64 + (bid >> 3);
    const int row0 = (swz >> 2) * 128;
    const int nb = swz & 3;

    floatx4 accA[4][3], accB[4][3];
    #pragma unroll
    for (int a = 0; a < 4; ++a)
        #pragma unroll
        for (int b = 0; b < 3; ++b) {
            accA[a][b] = (floatx4){0.f, 0.f, 0.f, 0.f};
            accB[a][b] = (floatx4){0.f, 0.f, 0.f, 0.f};
        }

    const int slr = lane >> 2;
    const int slc = (lane & 3) * 8;
    const int fr = lane & 15;
    const int fk = (lane >> 4) * 8;

    const int nkt = first ? 8 : 12;
    for (int kt8 = 0; kt8 < nkt; ++kt8) {
        const int kb = kt8 * 32;
        for (int i = w; i < 6; i += 4)
            GLOAD16(WT + (size_t)(nb * 96 + i * 16 + slr) * 384 + kb + slc, &Bs[i * 16 * 32]);
        if (kt8 < 8) {
            #pragma unroll
            for (int i = 0; i < 2; ++i) {
                const int r = w * 32 + i * 16;
                GLOAD16(hx + (size_t)(row0 + r + slr) * 256 + kb + slc, &As[r * 32]);
            }
        } else {
            #pragma unroll
            for (int i = 0; i < 2; ++i) {
                const int r = w * 32 + i * 16;
                GLOAD16(g16_prev + (size_t)(row0 + r + slr) * 128 + (kb - 256) + slc, &As[r * 32]);
            }
        }
        __syncthreads();
        half8 af[4], bf[3];
        #pragma unroll
        for (int mi = 0; mi < 4; ++mi)
            af[mi] = *(const half8*)&As[(wy * 64 + mi * 16 + fr) * 32 + fk];
        #pragma unroll
        for (int ni = 0; ni < 3; ++ni)
            bf[ni] = *(const half8*)&Bs[(wx * 48 + ni * 16 + fr) * 32 + fk];
        if (kt8 < 8) {
            #pragma unroll
            for (int mi = 0; mi < 4; ++mi)
                #pragma unroll
                for (int ni = 0; ni < 3; ++ni)
                    accA[mi][ni] = __builtin_amdgcn_mfma_f32_16x16x32_f16(af[mi], bf[ni], accA[mi][ni], 0, 0, 0);
        } else {
            #pragma unroll
            for (int mi = 0; mi < 4; ++mi)
                #pragma unroll
                for (int ni = 0; ni < 3; ++ni)
                    accB[mi][ni] = __builtin_amdgcn_mfma_f32_16x16x32_f16(af[mi], bf[ni], accB[mi][ni], 0, 0, 0);
        }
        __syncthreads();
    }

    const int U = nb * 32 + wx * 16 + fr;
    const bool uv = U < H2c;
    const float bzi = uv ? b_in[U] : 0.f;
    const float bri = uv ? b_in[H2c + U] : 0.f;
    const float bhi = uv ? b_in[2 * H2c + U] : 0.f;
    const float bzr = uv ? b_rec[U] : 0.f;
    const float brr = uv ? b_rec[H2c + U] : 0.f;
    const float bhr = uv ? b_rec[2 * H2c + U] : 0.f;
    const int rbase = row0 + wy * 64 + (lane >> 4) * 4;
    #pragma unroll
    for (int mi = 0; mi < 4; ++mi) {
        #pragma unroll
        for (int r = 0; r < 4; ++r) {
            const int row = rbase + mi * 16 + r;
            const float gp = (!first && uv) ? g_prev[(size_t)row * H2c + U] : 0.f;
            const float mxz = accA[mi][0][r] + bzi;
            const float mxr = accA[mi][1][r] + bri;
            const float mxh = accA[mi][2][r] + bhi;
            const float mhz = accB[mi][0][r] + bzr;
            const float mhr = accB[mi][1][r] + brr;
            const float mhh = accB[mi][2][r] + bhr;
            const float z = sigm(mxz + mhz);
            const float rr = sigm(mxr + mhr);
            const float hc = fmaxf(mxh + rr * mhh, 0.f);
            const float g = z * gp + (1.f - z) * hc;
            if (uv) g_out[(size_t)row * H2c + U] = g;
            g16_out[(size_t)row * 128 + U] = uv ? (_Float16)g : (_Float16)0.f;
        }
    }
}

// ---------------------------------------------------------------------------
// Dense: out = relu(g @ Wd + bd), [B,100]@[100,10]
// ---------------------------------------------------------------------------
__global__ __launch_bounds__(256)
void dense_out(const float* __restrict__ hg, const float* __restrict__ Wd,
               const float* __restrict__ bd, float* __restrict__ out)
{
    __shared__ float wd_s[H2c * TT];
    __shared__ float bd_s[TT];
    const int tid = threadIdx.x;
    for (int i = tid; i < H2c * TT; i += 256) wd_s[i] = Wd[i];
    if (tid < TT) bd_s[tid] = bd[tid];
    __syncthreads();

    const int row = blockIdx.x * 256 + tid;
    float acc[TT];
    #pragma unroll
    for (int j = 0; j < TT; ++j) acc[j] = 0.f;
    const float* hrow = hg + (size_t)row * H2c;
    for (int k = 0; k < H2c; ++k) {
        float xv = hrow[k];
        #pragma unroll
        for (int j = 0; j < TT; ++j) acc[j] += xv * wd_s[k * TT + j];
    }
    #pragma unroll
    for (int j = 0; j < TT; ++j)
        out[(size_t)row * TT + j] = fmaxf(acc[j] + bd_s[j], 0.f);
}

// ---------------------------------------------------------------------------
extern "C" void kernel_launch(void* const* d_in, const int* in_sizes, int n_in,
                              void* d_out, int out_size, void* d_ws, size_t ws_size,
                              hipStream_t stream)
{
    const float* noise  = (const float*)d_in[0];
    const float* Wx_l   = (const float*)d_in[1];
    const float* Wh_l   = (const float*)d_in[2];
    const float* b_l    = (const float*)d_in[3];
    const float* Wx_g   = (const float*)d_in[4];
    const float* Wh_g   = (const float*)d_in[5];
    const float* b_in   = (const float*)d_in[6];
    const float* b_rec  = (const float*)d_in[7];
    const float* Wd     = (const float*)d_in[8];
    const float* bd     = (const float*)d_in[9];
    float* outf = (float*)d_out;

    char* p = (char*)d_ws;
    auto alloc = [&](size_t bytes) {
        char* r = p;
        p += (bytes + 255) & ~(size_t)255;
        return r;
    };
    _Float16* WTx  = (_Float16*)alloc((size_t)1024 * 512 * 2);
    _Float16* WTh  = (_Float16*)alloc((size_t)1024 * 256 * 2);
    _Float16* WTg  = (_Float16*)alloc((size_t)384 * 384 * 2);
    _Float16* xc   = (_Float16*)alloc((size_t)Bsz * TT * 512 * 2);  // 168 MB
    _Float16* ZX   = (_Float16*)alloc((size_t)Bsz * TT * 1024 * 2); // 336 MB
    _Float16* h16A = (_Float16*)alloc((size_t)Bsz * 256 * 2);
    _Float16* h16B = (_Float16*)alloc((size_t)Bsz * 256 * 2);
    float*    cA   = (float*)alloc((size_t)Bsz * 256 * 4);
    float*    cB   = (float*)alloc((size_t)Bsz * 256 * 4);
    float*    gA   = (float*)alloc((size_t)Bsz * 100 * 4);
    float*    gB   = (float*)alloc((size_t)Bsz * 100 * 4);
    _Float16* g16A = (_Float16*)alloc((size_t)Bsz * 128 * 2);
    _Float16* g16B = (_Float16*)alloc((size_t)Bsz * 128 * 2);

    conv_all<<<Bsz * TT * 64 / 256, 256, 0, stream>>>(noise, xc);
    prep_lstm_w<<<1024 * 768 / 256, 256, 0, stream>>>(Wx_l, Wh_l, WTx, WTh);
    prep_gru_w<<<(384 * 384 + 255) / 256, 256, 0, stream>>>(Wx_g, Wh_g, WTg);
    big_gemm<<<10240, 256, 0, stream>>>(xc, WTx, ZX);

    _Float16 *h_r = h16B, *h_w = h16A;
    float *c_r = cB, *c_w = cA;
    float *g_r = gB, *g_w = gA;
    _Float16 *g16_r = g16B, *g16_w = g16A;
    float* g_last = gA;

    for (int t = 0; t < TT; ++t) {
        lstm_rec<<<1024, 256, 0, stream>>>(
            ZX + (size_t)t * Bsz * 1024, WTh, b_l, h_r, c_r, h_w, c_w, t == 0 ? 1 : 0);
        gru_mfma<<<512, 256, 0, stream>>>(
            h_w, WTg, b_in, b_rec, g_r, g16_r, g_w, g16_w, t == 0 ? 1 : 0);
        g_last = g_w;
        _Float16* th;
        float* tf;
        th = h_r; h_r = h_w; h_w = th;
        tf = c_r; c_r = c_w; c_w = tf;
        tf = g_r; g_r = g_w; g_w = tf;
        th = g16_r; g16_r = g16_w; g16_w = th;
    }
    dense_out<<<Bsz / 256, 256, 0, stream>>>(g_last, Wd, bd, outf);
}